// Round 8
// baseline (450.724 us; speedup 1.0000x reference)
//
#include <hip/hip_runtime.h>

typedef __attribute__((ext_vector_type(8))) short short8;
typedef __attribute__((ext_vector_type(4))) float f32x4;

constexpr int Bb = 256, Ss = 512, Kk = 32, Ff = 64, H1 = 512, H2 = 256;
constexpr int KD1E = 2080;   // 2048 + 32 (dist fold)

#define DEVI static __device__ __forceinline__
#define BARRIER asm volatile("s_barrier" ::: "memory")
#define VMCNT(N) asm volatile("s_waitcnt vmcnt(" #N ")" ::: "memory")

DEVI unsigned short f2b(float f) {
  unsigned u = __float_as_uint(f);
  return (unsigned short)((u + 0x7FFFu + ((u >> 16) & 1u)) >> 16);
}

DEVI void stage16(const void* g, void* l) {
  __builtin_amdgcn_global_load_lds((const __attribute__((address_space(1))) void*)g,
                                   (__attribute__((address_space(3))) void*)l, 16, 0, 0);
}

// ---------- precompute ----------
__global__ void k_cvt_x(const float* __restrict__ x, unsigned short* __restrict__ xbf) {
  int i = blockIdx.x * 256 + threadIdx.x;
  float4 v = ((const float4*)x)[i];
  ushort4 o;
  o.x = f2b(v.x); o.y = f2b(v.y); o.z = f2b(v.z); o.w = f2b(v.w);
  ((ushort4*)xbf)[i] = o;
}

__global__ void k_cvt_dist(const float* __restrict__ dist, unsigned short* __restrict__ distbf) {
  int i = blockIdx.x * 256 + threadIdx.x;  // 4096 threads x float4
  float4 v = ((const float4*)dist)[i];
  ushort4 o;
  o.x = f2b(v.x); o.y = f2b(v.y); o.z = f2b(v.z); o.w = f2b(v.w);
  ((ushort4*)distbf)[i] = o;
}

// w1t[h][k] : k<2048 -> W1[(k>>6)*65 + (k&63)][h] ; k in [2048,2080) -> W1[(k-2048)*65+64][h]
__global__ void k_w1t(const float* __restrict__ W1, unsigned short* __restrict__ w1t) {
  int h = blockIdx.x;
  for (int k = threadIdx.x; k < KD1E; k += 256) {
    int row = (k < 2048) ? ((k >> 6) * 65 + (k & 63)) : ((k - 2048) * 65 + 64);
    w1t[h * KD1E + k] = f2b(W1[row * 512 + h]);
  }
}

__global__ void k_w2t(const float* __restrict__ W2, unsigned short* __restrict__ w2t) {
  int idx = blockIdx.x * 256 + threadIdx.x;  // 256*512
  int n = idx >> 9, k = idx & 511;
  w2t[idx] = f2b(W2[k * 256 + n]);
}

// ---------- fused: h2 = relu(gather(x)+dist @ W1e) @ W2, max over s, per batch ----------
// Block: one batch b, s-rows [s0, s0+128), full 512 h-cols. 512 thr / 8 waves (2m x 4n).
// Main K-loop: 65 windows of K=32 (window 64 = dist fold). 3-slot rotation
// (A 8KB + B 32KB = 40KB/slot), 1 barrier/window, VMCNT(6) counted ledger.
// LDS chunk swizzle (R4-proven): stored 16B-chunk q of row r holds global chunk q^(r&3);
// linear gload_lds dest, swizzle on global src + read addr (rule #21).
__global__ __launch_bounds__(512, 1) void k_fused(
    const unsigned short* __restrict__ xbf, const unsigned short* __restrict__ w1t,
    const int* __restrict__ nb, const unsigned short* __restrict__ distbf,
    const float* __restrict__ b1, const unsigned short* __restrict__ w2t,
    const float* __restrict__ b2, unsigned* __restrict__ mrelu) {
  __shared__ __align__(16) char smem[147456];  // 144 KB: slots 3x40960 | later h1lds 128K + B2 16K
  const int tid = threadIdx.x;
  const int lane = tid & 63;
  const int w = tid >> 6;
  const int wm = w >> 2, wn = w & 3;           // 2m x 4n
  const int b = blockIdx.x >> 2;
  const int s0 = (blockIdx.x & 3) << 7;

  // staging geometry: thread -> (row = tid>>2, chunk-pos = tid&3), src chunk = pos^(row&3)
  const int arow = tid >> 2;
  const int aCs = (((tid & 3) ^ ((tid >> 2) & 3)) << 3);  // swizzled src chunk (elems)
  const int nbB = (s0 + arow) << 5;                        // nb row base
  // frag-read geometry (16B-aligned, XOR chunk): shared by main A/B and phase-B B2
  const int rB = ((lane & 15) << 6) + ((((lane >> 4) ^ (lane & 3))) << 4);

  f32x4 acc[4][8];
  #pragma unroll
  for (int m = 0; m < 4; ++m)
    #pragma unroll
    for (int n = 0; n < 8; ++n) acc[m][n] = (f32x4){0.f, 0.f, 0.f, 0.f};

#define STAGE_WIN(WIN, SLOT, JR)                                                  \
  {                                                                               \
    const int HS = ((WIN) < 64) ? (WIN) : 64;                                     \
    char* sl = smem + (SLOT) * 40960;                                             \
    if (HS < 64) {                                                                \
      stage16(xbf + ((size_t)(((b << 9) + (JR)) << 6) + ((HS & 1) << 5) + aCs),   \
              sl + (tid << 4));                                                   \
    } else {                                                                      \
      stage16(distbf + (((s0 + arow) << 5) + aCs), sl + (tid << 4));              \
    }                                                                             \
    const unsigned short* bbp = w1t + (HS << 5) + aCs;                            \
    stage16(bbp + (size_t)(arow)       * KD1E, sl + 8192 + (tid << 4));           \
    stage16(bbp + (size_t)(arow + 128) * KD1E, sl + 16384 + (tid << 4));          \
    stage16(bbp + (size_t)(arow + 256) * KD1E, sl + 24576 + (tid << 4));          \
    stage16(bbp + (size_t)(arow + 384) * KD1E, sl + 32768 + (tid << 4));          \
  }

  // prologue: j for windows 0,1 (t=0) and 2,3 (t=1); stage windows 0,1
  int j01 = nb[nbB];
  int jreg = nb[nbB + 1];
  STAGE_WIN(0, 0, j01);
  STAGE_WIN(1, 1, j01);
  VMCNT(0);

  int csl = 0, psl = 2;
  #pragma unroll 1
  for (int W = 0; W < 65; ++W) {
    BARRIER;  // publishes window W (drained by VMCNT(6) of iter W-1 / prologue)
    // prefetch j for next iter's stage (oldest in queue -> cheap waits)
    int jn = nb[nbB + (((W + 3) >> 1) < 32 ? ((W + 3) >> 1) : 31)];
    const char* sl = smem + csl * 40960;
    short8 af[4], bf[8];
    #pragma unroll
    for (int m = 0; m < 4; ++m)
      af[m] = *(const short8*)(sl + (wm << 12) + (m << 10) + rB);
    #pragma unroll
    for (int n = 0; n < 8; ++n)
      bf[n] = *(const short8*)(sl + 8192 + (wn << 13) + (n << 10) + rB);
    STAGE_WIN(W + 2, psl, jreg);
    VMCNT(6);  // window W+1's 5 stages + old j retired; W+2's 5 + jn remain
    __builtin_amdgcn_s_setprio(1);
    #pragma unroll
    for (int m = 0; m < 4; ++m)
      #pragma unroll
      for (int n = 0; n < 8; ++n)
        acc[m][n] = __builtin_amdgcn_mfma_f32_16x16x32_bf16(af[m], bf[n], acc[m][n], 0, 0, 0);
    __builtin_amdgcn_s_setprio(0);
    jreg = jn;
    csl = (csl == 2) ? 0 : csl + 1;
    psl = (psl == 2) ? 0 : psl + 1;
  }
#undef STAGE_WIN
  VMCNT(0);   // drain dup stages before overwriting slot region as h1lds
  BARRIER;

  // ---- phase A: relu(acc + b1) -> bf16 h1lds[128][512], byte-XOR ((row&7)<<4)
  {
    float b1v[8];
    #pragma unroll
    for (int n = 0; n < 8; ++n) b1v[n] = b1[(wn << 7) + (n << 4) + (lane & 15)];
    #pragma unroll
    for (int m = 0; m < 4; ++m) {
      #pragma unroll
      for (int n = 0; n < 8; ++n) {
        const int col = (wn << 7) + (n << 4) + (lane & 15);
        #pragma unroll
        for (int r = 0; r < 4; ++r) {
          const int row = (wm << 6) + (m << 4) + ((lane >> 4) << 2) + r;
          float v = acc[m][n][r] + b1v[n];
          v = v > 0.f ? v : 0.f;
          unsigned off = (unsigned)(((row << 10) + (col << 1)) ^ ((row & 7) << 4));
          *(unsigned short*)(smem + off) = f2b(v);
        }
      }
    }
  }
  BARRIER;

  // ---- phase B: h2(128x256) = h1lds @ w2t^T, 16 k-chunks of 32
  f32x4 acc2[4][4];
  #pragma unroll
  for (int m = 0; m < 4; ++m)
    #pragma unroll
    for (int n = 0; n < 4; ++n) acc2[m][n] = (f32x4){0.f, 0.f, 0.f, 0.f};

  for (int kc = 0; kc < 16; ++kc) {
    // stage B2 = w2t[256 outs][k-chunk 32] -> smem+131072 (16KB), 2 loads/thread
    {
      const unsigned short* src = w2t + (kc << 5) + aCs;
      stage16(src + (size_t)(arow) * 512,       smem + 131072 + (tid << 4));
      stage16(src + (size_t)(arow + 128) * 512, smem + 139264 + (tid << 4));
    }
    VMCNT(0);
    BARRIER;
    short8 a2[4], b2f[4];
    #pragma unroll
    for (int m = 0; m < 4; ++m) {
      const int row = (wm << 6) + (m << 4) + (lane & 15);
      a2[m] = *(const short8*)(smem + ((((row << 10) + (kc << 6) + ((lane >> 4) << 4))
                                       ^ ((lane & 7) << 4))));
    }
    #pragma unroll
    for (int n = 0; n < 4; ++n)
      b2f[n] = *(const short8*)(smem + 131072 + (wn << 12) + (n << 10) + rB);
    #pragma unroll
    for (int m = 0; m < 4; ++m)
      #pragma unroll
      for (int n = 0; n < 4; ++n)
        acc2[m][n] = __builtin_amdgcn_mfma_f32_16x16x32_bf16(a2[m], b2f[n], acc2[m][n], 0, 0, 0);
    BARRIER;  // before next chunk's stage overwrites B2
  }

  // ---- phase C: col-max over 128 s-rows, +b2, relu, atomicMax per (b,col)
  #pragma unroll
  for (int n = 0; n < 4; ++n) {
    const int col = (wn << 6) + (n << 4) + (lane & 15);
    float cm = -1e30f;
    #pragma unroll
    for (int m = 0; m < 4; ++m)
      #pragma unroll
      for (int r = 0; r < 4; ++r) cm = fmaxf(cm, acc2[m][n][r]);
    cm = fmaxf(cm, __shfl_xor(cm, 16));
    cm = fmaxf(cm, __shfl_xor(cm, 32));
    if ((lane >> 4) == 0) {
      float v = fmaxf(cm + b2[col], 0.f);
      atomicMax(mrelu + ((b << 8) + col), __float_as_uint(v));
    }
  }
}

// ---------- final: out[b] = relu(m[b,:]) . Wd + bd ----------
__global__ void k_final(const unsigned* __restrict__ mrelu, const float* __restrict__ wd,
                        const float* __restrict__ bd, float* __restrict__ out) {
  int b = blockIdx.x, t = threadIdx.x;
  float v = __uint_as_float(mrelu[(b << 8) + t]) * wd[t];
  #pragma unroll
  for (int o = 32; o > 0; o >>= 1) v += __shfl_down(v, o);
  __shared__ float p[4];
  if ((t & 63) == 0) p[t >> 6] = v;
  __syncthreads();
  if (t == 0) out[b] = p[0] + p[1] + p[2] + p[3] + bd[0];
}

extern "C" void kernel_launch(void* const* d_in, const int* in_sizes, int n_in,
                              void* d_out, int out_size, void* d_ws, size_t ws_size,
                              hipStream_t stream) {
  (void)in_sizes; (void)n_in; (void)out_size; (void)ws_size;
  const float* x    = (const float*)d_in[0];
  const int*   nb   = (const int*)d_in[1];
  const float* dist = (const float*)d_in[2];
  const float* W1   = (const float*)d_in[3];
  const float* b1   = (const float*)d_in[4];
  const float* W2   = (const float*)d_in[5];
  const float* b2   = (const float*)d_in[6];
  const float* Wd   = (const float*)d_in[7];
  const float* bd   = (const float*)d_in[8];
  float* out = (float*)d_out;

  // ws usage ~19.5 MB
  char* p = (char*)d_ws;
  unsigned short* xbf    = (unsigned short*)p; p += (size_t)Bb * Ss * Ff * 2;   // 16 MB
  unsigned short* w1t    = (unsigned short*)p; p += (size_t)H1 * KD1E * 2;      // 2.13 MB
  unsigned short* w2t    = (unsigned short*)p; p += (size_t)H2 * H1 * 2;        // 0.25 MB
  unsigned short* distbf = (unsigned short*)p; p += (size_t)Ss * Kk * 2;        // 32 KB
  unsigned*       mrelu  = (unsigned*)p;       p += (size_t)Bb * H2 * 4;        // 0.25 MB

  hipMemsetAsync(mrelu, 0, (size_t)Bb * H2 * 4, stream);
  k_cvt_x<<<(Bb * Ss * Ff / 4) / 256, 256, 0, stream>>>(x, xbf);
  k_cvt_dist<<<(Ss * Kk / 4) / 256, 256, 0, stream>>>(dist, distbf);
  k_w1t<<<H1, 256, 0, stream>>>(W1, w1t);
  k_w2t<<<(H2 * H1) / 256, 256, 0, stream>>>(W2, w2t);
  k_fused<<<Bb * 4, 512, 0, stream>>>(xbf, w1t, nb, distbf, b1, w2t, b2, mrelu);
  k_final<<<Bb, 256, 0, stream>>>(mrelu, Wd, bd, out);
}